// Round 10
// baseline (26.502 us; speedup 1.0000x reference)
//
#include <hip/hip_runtime.h>

// Bottom-up HTMM forward. One block per (tree, generator); 16 groups of 16
// lanes. Group grp evaluates sibling subtrees {2grp,2grp+1} as one float2
// register chain, finishing with their level-4 parent in-chain. 16x16 matvec
// via hand-fused v_fmac_f32_dpp (row_ror); reductions via v_add_f32_dpp.
// Nodes return RAW beliefs; the parent reduces both children with ONE
// grpsum4 (batched), logs log2(nuL*nuR), and rcp-combines. Exact same math
// as the per-node-normalized version, fewer reduce passes.
#define G_   8
#define NT_  128
#define NPT_ 1023

typedef float f16v __attribute__((ext_vector_type(16)));
#define RCP(x) __builtin_amdgcn_rcpf(x)

// lane i receives v[(i - R) & 15] within its 16-lane row (row_ror)
template<int R>
__device__ __forceinline__ float rotr16(float v) {
  return __int_as_float(__builtin_amdgcn_update_dpp(
      0, __float_as_int(v), 0x120 | R, 0xF, 0xF, true));
}
// builtin-path reduces (compiler handles DPP hazards) — prologue/top only
__device__ __forceinline__ float grpsum16(float v) {
  v += rotr16<8>(v); v += rotr16<4>(v); v += rotr16<2>(v); v += rotr16<1>(v);
  return v;
}
__device__ __forceinline__ float grpmax16(float v) {
  v = fmaxf(v, rotr16<8>(v)); v = fmaxf(v, rotr16<4>(v));
  v = fmaxf(v, rotr16<2>(v)); v = fmaxf(v, rotr16<1>(v));
  return v;
}

// ---- hot path: 4 dots with fused v_fmac_f32_dpp. Round-robin over 4
// accumulators: self-dep distance 4 >= FMA latency; s_nop 1 guards entry.
#define FMAC4_R(R) \
  asm("v_fmac_f32_dpp %0, %4, %8 row_ror:" #R " row_mask:0xf bank_mask:0xf\n\t" \
      "v_fmac_f32_dpp %1, %5, %8 row_ror:" #R " row_mask:0xf bank_mask:0xf\n\t" \
      "v_fmac_f32_dpp %2, %6, %9 row_ror:" #R " row_mask:0xf bank_mask:0xf\n\t" \
      "v_fmac_f32_dpp %3, %7, %9 row_ror:" #R " row_mask:0xf bank_mask:0xf"     \
      : "+v"(aLx), "+v"(aLy), "+v"(aRx), "+v"(aRy)                              \
      : "v"(vLx), "v"(vLy), "v"(vRx), "v"(vRy), "v"(w0[R]), "v"(w1[R]))
#define FMAC4_FIRST(R) \
  asm("s_nop 1\n\t"                                                             \
      "v_fmac_f32_dpp %0, %4, %8 row_ror:" #R " row_mask:0xf bank_mask:0xf\n\t" \
      "v_fmac_f32_dpp %1, %5, %8 row_ror:" #R " row_mask:0xf bank_mask:0xf\n\t" \
      "v_fmac_f32_dpp %2, %6, %9 row_ror:" #R " row_mask:0xf bank_mask:0xf\n\t" \
      "v_fmac_f32_dpp %3, %7, %9 row_ror:" #R " row_mask:0xf bank_mask:0xf"     \
      : "+v"(aLx), "+v"(aLy), "+v"(aRx), "+v"(aRy)                              \
      : "v"(vLx), "v"(vLy), "v"(vRx), "v"(vRy), "v"(w0[R]), "v"(w1[R]))

__device__ __forceinline__ void dot4(float vLx, float vLy, float vRx, float vRy,
                                     const f16v& w0, const f16v& w1,
                                     float& oLx, float& oLy, float& oRx, float& oRy) {
  float aLx = vLx * w0[0];
  float aLy = vLy * w0[0];
  float aRx = vRx * w1[0];
  float aRy = vRy * w1[0];
  FMAC4_FIRST(1);
  FMAC4_R(2);  FMAC4_R(3);  FMAC4_R(4);  FMAC4_R(5);
  FMAC4_R(6);  FMAC4_R(7);  FMAC4_R(8);  FMAC4_R(9);
  FMAC4_R(10); FMAC4_R(11); FMAC4_R(12); FMAC4_R(13);
  FMAC4_R(14); FMAC4_R(15);
  oLx = aLx; oLy = aLy; oRx = aRx; oRy = aRy;
}

// ---- 2 dots fused (parent node + top phase)
#define FMAC2_R(R) \
  asm("v_fmac_f32_dpp %0, %2, %4 row_ror:" #R " row_mask:0xf bank_mask:0xf\n\t" \
      "v_fmac_f32_dpp %1, %3, %5 row_ror:" #R " row_mask:0xf bank_mask:0xf"     \
      : "+v"(aL), "+v"(aR)                                                      \
      : "v"(vL), "v"(vR), "v"(w0[R]), "v"(w1[R]))
#define FMAC2_FIRST(R) \
  asm("s_nop 1\n\t"                                                             \
      "v_fmac_f32_dpp %0, %2, %4 row_ror:" #R " row_mask:0xf bank_mask:0xf\n\t" \
      "v_fmac_f32_dpp %1, %3, %5 row_ror:" #R " row_mask:0xf bank_mask:0xf"     \
      : "+v"(aL), "+v"(aR)                                                      \
      : "v"(vL), "v"(vR), "v"(w0[R]), "v"(w1[R]))

__device__ __forceinline__ void dot2f(float vL, float vR,
                                      const f16v& w0, const f16v& w1,
                                      float& oL, float& oR) {
  float aL = vL * w0[0];
  float aR = vR * w1[0];
  FMAC2_FIRST(1);
  FMAC2_R(2);  FMAC2_R(3);  FMAC2_R(4);  FMAC2_R(5);
  FMAC2_R(6);  FMAC2_R(7);  FMAC2_R(8);  FMAC2_R(9);
  FMAC2_R(10); FMAC2_R(11); FMAC2_R(12); FMAC2_R(13);
  FMAC2_R(14); FMAC2_R(15);
  oL = aL; oR = aR;
}

// dual 16-lane sum via v_add_f32_dpp; s_nops cover the same-reg
// VALU-write -> DPP-read hazard the compiler can't see.
__device__ __forceinline__ void grpsum2(float rx, float ry, float& nux, float& nuy) {
  asm("s_nop 1\n\t"
      "v_add_f32_dpp %0, %2, %2 row_ror:8 row_mask:0xf bank_mask:0xf\n\t"
      "v_add_f32_dpp %1, %3, %3 row_ror:8 row_mask:0xf bank_mask:0xf\n\t"
      "s_nop 0\n\t"
      "v_add_f32_dpp %0, %0, %0 row_ror:4 row_mask:0xf bank_mask:0xf\n\t"
      "v_add_f32_dpp %1, %1, %1 row_ror:4 row_mask:0xf bank_mask:0xf\n\t"
      "s_nop 0\n\t"
      "v_add_f32_dpp %0, %0, %0 row_ror:2 row_mask:0xf bank_mask:0xf\n\t"
      "v_add_f32_dpp %1, %1, %1 row_ror:2 row_mask:0xf bank_mask:0xf\n\t"
      "s_nop 0\n\t"
      "v_add_f32_dpp %0, %0, %0 row_ror:1 row_mask:0xf bank_mask:0xf\n\t"
      "v_add_f32_dpp %1, %1, %1 row_ror:1 row_mask:0xf bank_mask:0xf"
      : "=&v"(nux), "=&v"(nuy)
      : "v"(rx), "v"(ry));
}

// quad 16-lane sum: 4 interleaved DPP chains, round-robin distance 4;
// s_nop 1 at entry guards freshly-written inputs.
__device__ __forceinline__ void grpsum4(float r0, float r1, float r2, float r3,
                                        float& n0, float& n1, float& n2, float& n3) {
  asm("s_nop 1\n\t"
      "v_add_f32_dpp %0, %4, %4 row_ror:8 row_mask:0xf bank_mask:0xf\n\t"
      "v_add_f32_dpp %1, %5, %5 row_ror:8 row_mask:0xf bank_mask:0xf\n\t"
      "v_add_f32_dpp %2, %6, %6 row_ror:8 row_mask:0xf bank_mask:0xf\n\t"
      "v_add_f32_dpp %3, %7, %7 row_ror:8 row_mask:0xf bank_mask:0xf\n\t"
      "v_add_f32_dpp %0, %0, %0 row_ror:4 row_mask:0xf bank_mask:0xf\n\t"
      "v_add_f32_dpp %1, %1, %1 row_ror:4 row_mask:0xf bank_mask:0xf\n\t"
      "v_add_f32_dpp %2, %2, %2 row_ror:4 row_mask:0xf bank_mask:0xf\n\t"
      "v_add_f32_dpp %3, %3, %3 row_ror:4 row_mask:0xf bank_mask:0xf\n\t"
      "v_add_f32_dpp %0, %0, %0 row_ror:2 row_mask:0xf bank_mask:0xf\n\t"
      "v_add_f32_dpp %1, %1, %1 row_ror:2 row_mask:0xf bank_mask:0xf\n\t"
      "v_add_f32_dpp %2, %2, %2 row_ror:2 row_mask:0xf bank_mask:0xf\n\t"
      "v_add_f32_dpp %3, %3, %3 row_ror:2 row_mask:0xf bank_mask:0xf\n\t"
      "v_add_f32_dpp %0, %0, %0 row_ror:1 row_mask:0xf bank_mask:0xf\n\t"
      "v_add_f32_dpp %1, %1, %1 row_ror:1 row_mask:0xf bank_mask:0xf\n\t"
      "v_add_f32_dpp %2, %2, %2 row_ror:1 row_mask:0xf bank_mask:0xf\n\t"
      "v_add_f32_dpp %3, %3, %3 row_ror:1 row_mask:0xf bank_mask:0xf"
      : "=&v"(n0), "=&v"(n1), "=&v"(n2), "=&v"(n3)
      : "v"(r0), "v"(r1), "v"(r2), "v"(r3));
}

// Post-order evaluation of two sibling depth-5 subtrees (float2 .x/.y).
// Returns this node's RAW belief (unnormalized). Children's nus are reduced
// HERE (one grpsum4 for both), logged pairwise, and rcp-folded into the
// combine — identical math to per-node normalization, fewer reduce passes.
template<int DELTA, int J>
__device__ __forceinline__ void evalN(const float* __restrict__ sBa,
                                      const f16v& w0, const f16v& w1,
                                      const f16v& lfx, const f16v& lfy,
                                      int intp, float2& ll, float2& raw) {
  // prefetch this node's B-gather before descending (hides LDS latency)
  int xp = __shfl(intp, (1 << DELTA) - 1 + J, 16);
  float bvA = sBa[xp & 0xFFFF];
  float bvB = sBa[((unsigned)xp) >> 16];
  float2 rawL, rawR;
  if constexpr (DELTA == 3) {
    rawL.x = lfx[2 * J];     rawL.y = lfy[2 * J];
    rawR.x = lfx[2 * J + 1]; rawR.y = lfy[2 * J + 1];
  } else {
    evalN<DELTA + 1, 2 * J>(sBa, w0, w1, lfx, lfy, intp, ll, rawL);
    evalN<DELTA + 1, 2 * J + 1>(sBa, w0, w1, lfx, lfy, intp, ll, rawR);
  }
  float nLx, nLy, nRx, nRy;
  grpsum4(rawL.x, rawL.y, rawR.x, rawR.y, nLx, nLy, nRx, nRy);
  ll.x += __log2f(nLx * nRx);
  ll.y += __log2f(nLy * nRy);
  float rLx = RCP(nLx), rLy = RCP(nLy);
  float rRx = RCP(nRx), rRy = RCP(nRy);
  float dLx, dLy, dRx, dRy;
  dot4(rawL.x, rawL.y, rawR.x, rawR.y, w0, w1, dLx, dLy, dRx, dRy);
  raw.x = fmaf(dLx, rLx, dRx * rRx) * bvA;
  raw.y = fmaf(dLy, rLy, dRy * rRy) * bvB;
}

template<bool SYNC>
__device__ __forceinline__ void topStep(const float* __restrict__ child,
                                        float* parent, int U, int lvl,
                                        const float* __restrict__ sB,
                                        const f16v& w0, const f16v& w1,
                                        int a, int grp, int topx, float& ll) {
  int j = (grp < U) ? grp : 0;            // clamp: keep full-wave EXEC for DPP
  int node = (1 << lvl) - 1 + j;
  int xi = __shfl(topx, node, 64);
  float bval = sB[xi * 17 + a];
  float vL = child[(2 * j) * 17 + a];
  float vR = child[(2 * j + 1) * 17 + a];
  float dL, dR;
  dot2f(vL, vR, w0, w1, dL, dR);
  float bu = (dL + dR) * bval;
  float nu = grpsum16(bu);
  if (grp < U) {
    ll += __log2f(nu);
    if (parent) parent[grp * 17 + a] = bu * RCP(nu);
  }
  if constexpr (SYNC) __syncthreads();
}

__global__ __launch_bounds__(256, 4) void htmm_fwd_kernel(
    const float* __restrict__ lA,   // (16,16,2,8)
    const float* __restrict__ lB,   // (16,256,8)
    const float* __restrict__ lPi,  // (16,2,8)
    const float* __restrict__ lSP,  // (2,8)
    const int*   __restrict__ x,    // (128*1023,)
    float*       __restrict__ out)  // (128,8)
{
  __shared__ float sB[256 * 17];    // normalized B, [m][c], stride 17
  __shared__ float sA[2 * 16 * 16]; // normalized A, [l][b][a]
  __shared__ float sPi[32];         // [l][c]
  __shared__ float roots[16 * 17];  // level-4 beliefs (normalized)
  __shared__ float topA[8 * 17];
  __shared__ float topB[4 * 17];
  __shared__ float red[4];

  const int tid = threadIdx.x;
  const int bid = blockIdx.x;       // tree*8 + g
  const int T   = bid >> 3;
  const int g   = bid & 7;
  const int a   = tid & 15;
  const int grp = tid >> 4;
  const long base = (long)T * NPT_;
  const int sx = 2 * grp;           // left sibling subtree
  const int sy = 2 * grp + 1;       // right sibling subtree

  // ---- ALL global x loads first: latency hides under the softmax prologue --
  int lxA = x[base + 511 + 16 * sx + a] * 17;
  int lxB = x[base + 511 + 16 * sy + a] * 17;
  int leafp = lxA | (lxB << 16);
  int dpl = 31 - __clz(a + 1);
  int iA = (a < 15) ? x[base + ((31 + sx) << dpl) + a] * 17 : 0;
  int iB = (a < 15) ? x[base + ((31 + sy) << dpl) + a] * 17 : 0;
  int intp = iA | (iB << 16);
  int xpar = x[base + 15 + grp] * 17;                // level-4 parent obs
  int tl = tid & 63;
  int topx = x[base + (tl < 15 ? tl : 0)];           // x[0..14] in wave lanes

  // ---- SP softmax ----
  float s0 = lSP[g], s1 = lSP[G_ + g];
  float sm = fmaxf(s0, s1);
  float e0 = __expf(s0 - sm), e1 = __expf(s1 - sm);
  float inv = RCP(e0 + e1);
  const float SP0 = e0 * inv, SP1 = e1 * inv;

  // ---- A softmax over axis 0 (lanes = a), column b = grp ----
  #pragma unroll
  for (int l = 0; l < 2; ++l) {
    float v = lA[a * 256 + grp * 16 + l * 8 + g];
    float m = grpmax16(v);
    float e = __expf(v - m);
    float s = grpsum16(e);
    sA[(l * 16 + grp) * 16 + a] = e * RCP(s);
  }
  // ---- Pi softmax over axis 0 ----
  if (grp < 2) {
    float v = lPi[a * 16 + grp * 8 + g];
    float m = grpmax16(v);
    float e = __expf(v - m);
    float s = grpsum16(e);
    sPi[grp * 16 + a] = e * RCP(s);
  }
  // ---- B softmax over axis 1 (M): row c = grp, lane a covers m = a+16k ----
  {
    const int c = grp;
    float vv[16];
    float mx = -1e30f;
    #pragma unroll
    for (int k = 0; k < 16; ++k) {
      vv[k] = lB[c * (256 * G_) + (a + 16 * k) * G_ + g];
      mx = fmaxf(mx, vv[k]);
    }
    mx = grpmax16(mx);
    float ssum = 0.f;
    #pragma unroll
    for (int k = 0; k < 16; ++k) { vv[k] = __expf(vv[k] - mx); ssum += vv[k]; }
    ssum = grpsum16(ssum);
    float is = RCP(ssum);
    #pragma unroll
    for (int k = 0; k < 16; ++k) sB[(a + 16 * k) * 17 + c] = vv[k] * is;
  }
  __syncthreads();

  // ---- per-lane rotated weight vectors: w[r] = A[a][(a-r)&15][l] * SP[l] ----
  f16v w0, w1;
  #pragma unroll
  for (int r = 0; r < 16; ++r) {
    int b = (a - r) & 15;
    w0[r] = sA[b * 16 + a] * SP0;
    w1[r] = sA[(16 + b) * 16 + a] * SP1;
  }
  const float pi0 = sPi[a], pi1 = sPi[16 + a];
  const float* sBa = sB + a;

  // ---- leaf gathers, pipelined up front; leaves stay raw (Pi*B) ----
  f16v lfx, lfy;
  #pragma unroll
  for (int j = 0; j < 16; ++j) {
    int xp = __shfl(leafp, j, 16);
    float pi = (j & 1) ? pi1 : pi0;
    lfx[j] = pi * sBa[xp & 0xFFFF];
    lfy[j] = pi * sBa[((unsigned)xp) >> 16];
  }

  float2 ll = {0.f, 0.f};
  float2 raw5;
  evalN<0, 0>(sBa, w0, w1, lfx, lfy, intp, ll, raw5);

  // ---- in-chain level-4 parent: reduce both subtree roots, rcp-combine ----
  {
    float n5x, n5y;
    grpsum2(raw5.x, raw5.y, n5x, n5y);
    float r5x = RCP(n5x), r5y = RCP(n5y);
    float bvP = sBa[xpar];
    float dL, dR;
    dot2f(raw5.x, raw5.y, w0, w1, dL, dR);
    float praw = fmaf(dL, r5x, dR * r5y) * bvP;
    float nup = grpsum16(praw);
    ll.x += __log2f(n5x * n5y * nup);   // triple-paired log, >= ~1e-18
    roots[grp * 17 + a] = praw * RCP(nup);
  }
  __syncthreads();

  // ---- top 15 nodes (levels 3..0) ----
  float llt = 0.f;
  topStep<true >(roots, topA, 8, 3, sB, w0, w1, a, grp, topx, llt);
  topStep<true >(topA, topB, 4, 2, sB, w0, w1, a, grp, topx, llt);
  topStep<true >(topB, topA, 2, 1, sB, w0, w1, a, grp, topx, llt);
  topStep<false>(topA, nullptr, 1, 0, sB, w0, w1, a, grp, topx, llt);

  // ---- block reduce; scale: x16 lane duplication and log2 -> ln ----
  float v = ll.x + ll.y + llt;
  #pragma unroll
  for (int off = 32; off > 0; off >>= 1) v += __shfl_down(v, off, 64);
  if ((tid & 63) == 0) red[tid >> 6] = v;
  __syncthreads();
  if (tid == 0)
    out[bid] = (red[0] + red[1] + red[2] + red[3]) * (0.6931471805599453f / 16.f);
}

extern "C" void kernel_launch(void* const* d_in, const int* in_sizes, int n_in,
                              void* d_out, int out_size, void* d_ws, size_t ws_size,
                              hipStream_t stream) {
  const float* lA  = (const float*)d_in[0];
  const float* lB  = (const float*)d_in[1];
  const float* lPi = (const float*)d_in[2];
  const float* lSP = (const float*)d_in[3];
  const int*   x   = (const int*)d_in[4];
  float* out = (float*)d_out;
  htmm_fwd_kernel<<<dim3(NT_ * G_), dim3(256), 0, stream>>>(lA, lB, lPi, lSP, x, out);
}